// Round 7
// baseline (162.739 us; speedup 1.0000x reference)
//
#include <hip/hip_runtime.h>
#include <hip/hip_bf16.h>

// out[bn,e] = relu(relu(hp[bn]+ep[e]+b1) @ W2 + b2) @ W3 + b3
// R7: R4 topology (64-row x 512-col blocks, barrier-free K-loop, B streamed
// from L2, 2 blocks/CU) but 512 thr (8 waves -> 4 waves/SIMD latency hiding),
// mfma_f32_32x32x16_bf16 (2x FLOP/LDS-byte), and A staged in frag-record
// order (conflict-free, zero-VALU ds_reads).

typedef __attribute__((ext_vector_type(8))) short bf16x8;     // 8 bf16
typedef __attribute__((ext_vector_type(16))) float f32x16;    // 32x32 acc

static __device__ __forceinline__ ushort2 pk_bf16(float a, float b) {
  union { __hip_bfloat162 h; ushort2 u; } c;
  c.h = __float22bfloat162_rn(make_float2(a, b));
  return c.u;
}
static __device__ __forceinline__ float bf2f(unsigned short u) {
  union { unsigned int i; float f; } c;
  c.i = ((unsigned int)u) << 16;
  return c.f;
}

// ---------------- fused prep (352 blocks x 256 thr) ----------------
// blocks 0..255  : hpb rows (2/blk)  hpb[r][k] = bf16(sum_h h[r][h]*W1[h][k] + b1[k])
// blocks 256..287: epb rows (8/blk)  epb[e][k] = bf16(sum_d e[e][d]*W1[256+d][k])
// blocks 288..351: w2f pack, 32x32x16 B-frag records:
//   record(jg,ks) at w2f[((jg*32+ks)*64+l)*8]: lane l holds
//   W2[k = ks*16 + (l>>5)*8 + u][col = jg*32 + (l&31)], u=0..7
__global__ __launch_bounds__(256) void k_prep(
    const float* __restrict__ h_all, const float* __restrict__ e_feat,
    const float* __restrict__ W1, const float* __restrict__ b1,
    const float* __restrict__ W2,
    unsigned short* __restrict__ hpb, unsigned short* __restrict__ epb,
    unsigned short* __restrict__ w2f) {
  __shared__ float sm[64 * 68];   // 17408 B, reused per role
  const int t = threadIdx.x;
  const int b = blockIdx.x;

  if (b < 256) {                      // ---- hp part: 2 rows, bf16 out
    const int r0 = b * 2;
    float (*hs)[256] = (float(*)[256])sm;
    hs[0][t] = h_all[(size_t)r0 * 256 + t];
    hs[1][t] = h_all[(size_t)(r0 + 1) * 256 + t];
    __syncthreads();
    float2 a0 = make_float2(0.f, 0.f), a1 = make_float2(0.f, 0.f);
    #pragma unroll 2
    for (int k = 0; k < 256; k += 4) {
      float2 w0 = *(const float2*)(W1 + (size_t)k * 512 + 2 * t);
      float2 w1 = *(const float2*)(W1 + (size_t)(k + 1) * 512 + 2 * t);
      float2 w2v = *(const float2*)(W1 + (size_t)(k + 2) * 512 + 2 * t);
      float2 w3v = *(const float2*)(W1 + (size_t)(k + 3) * 512 + 2 * t);
      float h00 = hs[0][k], h01 = hs[0][k + 1], h02 = hs[0][k + 2], h03 = hs[0][k + 3];
      float h10 = hs[1][k], h11 = hs[1][k + 1], h12 = hs[1][k + 2], h13 = hs[1][k + 3];
      a0.x = fmaf(h00, w0.x, a0.x); a0.y = fmaf(h00, w0.y, a0.y);
      a1.x = fmaf(h10, w0.x, a1.x); a1.y = fmaf(h10, w0.y, a1.y);
      a0.x = fmaf(h01, w1.x, a0.x); a0.y = fmaf(h01, w1.y, a0.y);
      a1.x = fmaf(h11, w1.x, a1.x); a1.y = fmaf(h11, w1.y, a1.y);
      a0.x = fmaf(h02, w2v.x, a0.x); a0.y = fmaf(h02, w2v.y, a0.y);
      a1.x = fmaf(h12, w2v.x, a1.x); a1.y = fmaf(h12, w2v.y, a1.y);
      a0.x = fmaf(h03, w3v.x, a0.x); a0.y = fmaf(h03, w3v.y, a0.y);
      a1.x = fmaf(h13, w3v.x, a1.x); a1.y = fmaf(h13, w3v.y, a1.y);
    }
    float2 bv = *(const float2*)(b1 + 2 * t);
    *(ushort2*)(hpb + (size_t)r0 * 512 + 2 * t) = pk_bf16(a0.x + bv.x, a0.y + bv.y);
    *(ushort2*)(hpb + (size_t)(r0 + 1) * 512 + 2 * t) = pk_bf16(a1.x + bv.x, a1.y + bv.y);
  } else if (b < 288) {               // ---- ep part: 8 rows, bf16 out
    const int r0 = (b - 256) * 8;
    sm[t] = e_feat[(size_t)r0 * 64 + t];
    sm[256 + t] = e_feat[(size_t)r0 * 64 + 256 + t];
    __syncthreads();
    float2 acc[8];
    #pragma unroll
    for (int i = 0; i < 8; ++i) acc[i] = make_float2(0.f, 0.f);
    for (int k = 0; k < 64; ++k) {
      float2 wv = *(const float2*)(W1 + (size_t)(256 + k) * 512 + 2 * t);
      #pragma unroll
      for (int i = 0; i < 8; ++i) {
        acc[i].x = fmaf(sm[i * 64 + k], wv.x, acc[i].x);
        acc[i].y = fmaf(sm[i * 64 + k], wv.y, acc[i].y);
      }
    }
    #pragma unroll
    for (int i = 0; i < 8; ++i)
      *(ushort2*)(epb + (size_t)(r0 + i) * 512 + 2 * t) = pk_bf16(acc[i].x, acc[i].y);
  } else {                            // ---- w2f pack (32-col records)
    const int bb2 = b - 288;          // 0..63
    const int k0 = (bb2 >> 3) * 64;
    const int c0 = (bb2 & 7) * 64;
    // load 64x64 f32 tile: sm[kk*68 + cc] = W2[k0+kk][c0+cc]
    #pragma unroll
    for (int rr = 0; rr < 4; ++rr) {
      const int row = rr * 16 + (t >> 4);
      float4 v = *(const float4*)(W2 + (size_t)(k0 + row) * 512 + c0 + (t & 15) * 4);
      *(float4*)(&sm[row * 68 + (t & 15) * 4]) = v;
    }
    __syncthreads();
    #pragma unroll
    for (int s2 = 0; s2 < 2; ++s2) {
      const int s = t * 2 + s2;       // 0..511 (8 records x 64 lanes)
      const int rec = s >> 6, l = s & 63;
      const int jg = (c0 >> 5) + (rec & 1);
      const int ks = (k0 >> 4) + (rec >> 1);
      const int cl = (rec & 1) * 32 + (l & 31);
      const int kl = (rec >> 1) * 16 + (l >> 5) * 8;
      union { ushort2 o[4]; uint4 v; } u;
      #pragma unroll
      for (int uu = 0; uu < 4; ++uu)
        u.o[uu] = pk_bf16(sm[(kl + 2 * uu) * 68 + cl], sm[(kl + 2 * uu + 1) * 68 + cl]);
      *(uint4*)(w2f + ((size_t)(jg * 32 + ks) * 64 + l) * 8) = u.v;
    }
  }
}

// ---------------- main fused kernel ----------------
// 2048 blocks x 512 thr (8 waves). Block = 64 rows (one bn, e-quarter) x 512
// cols. Wave w: cols w*64 (2 col-tiles of 32). A tile in LDS in 32x32x16
// frag-record order: rec(rt,ks) -> 1KB, read at rec*1024 + lane*16.
__global__ __launch_bounds__(512, 4) void k_main(
    const unsigned short* __restrict__ hpb, const unsigned short* __restrict__ epb,
    const unsigned short* __restrict__ w2f, const float* __restrict__ b2,
    const float* __restrict__ W3, const float* __restrict__ b3,
    float* __restrict__ out) {
  __shared__ unsigned short x1s[64 * 512];   // 64 KiB, frag-record order
  __shared__ float osum[8][64];              // 2 KiB

  const int t = threadIdx.x;
  const int lane = t & 63;
  const int w = t >> 6;            // 0..7 -> col group (64 cols)
  const int l31 = lane & 31;
  const int half = lane >> 5;
  const int bn = blockIdx.x >> 2;
  const int e0 = (blockIdx.x & 3) << 6;

  // ---- B prefetch (ks=0,1) issued before staging, in flight across it
  const unsigned short* wrec0 = w2f + ((size_t)(w * 2 + 0) * 32 * 64 + lane) * 8;
  const unsigned short* wrec1 = w2f + ((size_t)(w * 2 + 1) * 32 * 64 + lane) * 8;
  bf16x8 bb[2][2];
  bb[0][0] = *(const bf16x8*)(wrec0);
  bb[0][1] = *(const bf16x8*)(wrec1);
  bb[1][0] = *(const bf16x8*)(wrec0 + 512);
  bb[1][1] = *(const bf16x8*)(wrec1 + 512);

  // ---- stage x1 into frag-record order: rec = (r>>5)*32 + (c>>1),
  //      slot = (r&31) + 32*(c&1); thread t: row r = t>>3, chunks c = (t&7)+8i
  {
    const int r = t >> 3;
    const int c8 = t & 7;
    const unsigned short* hrow = hpb + (size_t)bn * 512 + c8 * 8;
    const unsigned short* erow = epb + (size_t)(e0 + r) * 512 + c8 * 8;
    const int slot = (r & 31) + ((c8 & 1) << 5);
    const int rec0 = (r >> 5) * 32 + (c8 >> 1);
    #pragma unroll
    for (int i = 0; i < 8; ++i) {
      union { uint4 v; unsigned short s[8]; } hv, ev, ov;
      hv.v = *(const uint4*)(hrow + i * 64);
      ev.v = *(const uint4*)(erow + i * 64);
      #pragma unroll
      for (int u = 0; u < 4; ++u) {
        ushort2 p = pk_bf16(fmaxf(bf2f(ev.s[2 * u]) + bf2f(hv.s[2 * u]), 0.f),
                            fmaxf(bf2f(ev.s[2 * u + 1]) + bf2f(hv.s[2 * u + 1]), 0.f));
        ov.s[2 * u] = p.x;
        ov.s[2 * u + 1] = p.y;
      }
      *(uint4*)(&x1s[((rec0 + i * 4) * 64 + slot) * 8]) = ov.v;
    }
  }
  __syncthreads();

  // ---- barrier-free K-loop: 32 steps of K=16, 4 MFMAs (2 rt x 2 ct)
  f32x16 acc[2][2] = {};
  const unsigned short* abase = x1s + (size_t)lane * 8;
  #pragma unroll 8
  for (int ks = 0; ks < 32; ++ks) {
    const int cur = ks & 1;
    const int kn = (ks + 2) & 31;    // wraps at end: dummy reload, no OOB
    bf16x8 a0 = *(const bf16x8*)(abase + (size_t)(0 * 32 + ks) * 512);
    bf16x8 a1 = *(const bf16x8*)(abase + (size_t)(1 * 32 + ks) * 512);
    acc[0][0] = __builtin_amdgcn_mfma_f32_32x32x16_bf16(a0, bb[cur][0], acc[0][0], 0, 0, 0);
    acc[0][1] = __builtin_amdgcn_mfma_f32_32x32x16_bf16(a0, bb[cur][1], acc[0][1], 0, 0, 0);
    acc[1][0] = __builtin_amdgcn_mfma_f32_32x32x16_bf16(a1, bb[cur][0], acc[1][0], 0, 0, 0);
    acc[1][1] = __builtin_amdgcn_mfma_f32_32x32x16_bf16(a1, bb[cur][1], acc[1][1], 0, 0, 0);
    bb[cur][0] = *(const bf16x8*)(wrec0 + (size_t)kn * 512);
    bb[cur][1] = *(const bf16x8*)(wrec1 + (size_t)kn * 512);
  }

  // ---- fused epilogue: osum[row] = sum_n relu(acc + b2[n]) * W3[n]
  // C/D 32x32: col = lane&31, row = (reg&3) + 8*(reg>>2) + 4*(lane>>5)
  float b2v[2], w3v[2];
  #pragma unroll
  for (int ct = 0; ct < 2; ++ct) {
    const int n = w * 64 + ct * 32 + l31;
    b2v[ct] = b2[n];
    w3v[ct] = W3[n];
  }
  #pragma unroll
  for (int rt = 0; rt < 2; ++rt) {
    float part[16];
    #pragma unroll
    for (int g = 0; g < 16; ++g) {
      part[g] = fmaf(fmaxf(acc[rt][0][g] + b2v[0], 0.f), w3v[0], 0.f);
      part[g] = fmaf(fmaxf(acc[rt][1][g] + b2v[1], 0.f), w3v[1], part[g]);
    }
    #pragma unroll
    for (int g = 0; g < 16; ++g) {   // reduce over the 32 col-lanes
      float v = part[g];
      v += __shfl_xor(v, 1);
      v += __shfl_xor(v, 2);
      v += __shfl_xor(v, 4);
      v += __shfl_xor(v, 8);
      v += __shfl_xor(v, 16);
      part[g] = v;
    }
    if (l31 == 0) {
      #pragma unroll
      for (int g = 0; g < 16; ++g) {
        const int row = rt * 32 + (g & 3) + 8 * (g >> 2) + 4 * half;
        osum[w][row] = part[g];
      }
    }
  }
  __syncthreads();
  if (t < 64) {
    float s = b3[0];
    #pragma unroll
    for (int ww = 0; ww < 8; ++ww) s += osum[ww][t];
    out[(size_t)bn * 256 + e0 + t] = s;
  }
}

extern "C" void kernel_launch(void* const* d_in, const int* in_sizes, int n_in,
                              void* d_out, int out_size, void* d_ws, size_t ws_size,
                              hipStream_t stream) {
  const float* h_all  = (const float*)d_in[0];   // (8,64,256)
  const float* e_feat = (const float*)d_in[1];   // (256,64)
  const float* W1     = (const float*)d_in[2];   // (320,512)
  const float* b1     = (const float*)d_in[3];   // (512,)
  const float* W2     = (const float*)d_in[4];   // (512,512)
  const float* b2     = (const float*)d_in[5];   // (512,)
  const float* W3     = (const float*)d_in[6];   // (512,1)
  const float* b3     = (const float*)d_in[7];   // (1,)
  float* out = (float*)d_out;                    // 131072 f32

  // ws: hpb 512KB bf16 | epb 256KB bf16 | w2f 512KB bf16
  unsigned short* hpb = (unsigned short*)d_ws;
  unsigned short* epb = hpb + 512 * 512;
  unsigned short* w2f = epb + 256 * 512;

  hipLaunchKernelGGL(k_prep, dim3(352), dim3(256), 0, stream,
                     h_all, e_feat, W1, b1, W2, hpb, epb, w2f);
  hipLaunchKernelGGL(k_main, dim3(2048), dim3(512), 0, stream,
                     hpb, epb, w2f, b2, W3, b3, out);
}

// Round 8
// 159.815 us; speedup vs baseline: 1.0183x; 1.0183x over previous
//
#include <hip/hip_runtime.h>
#include <hip/hip_bf16.h>

// out[bn,e] = relu(relu(hp[bn]+ep[e]+b1) @ W2 + b2) @ W3 + b3
// R8: R7 skeleton (64x512 blocks, 512 thr, 32x32x16 MFMA, frag-record LDS,
// barrier-free K-loop) with: ep pre-laid in frag-record order (staging is a
// linear coalesced copy -> zero LDS write conflicts), all staging loads
// issued up front, and depth-4 B register prefetch ring.

typedef __attribute__((ext_vector_type(8))) short bf16x8;     // 8 bf16
typedef __attribute__((ext_vector_type(16))) float f32x16;    // 32x32 acc

static __device__ __forceinline__ ushort2 pk_bf16(float a, float b) {
  union { __hip_bfloat162 h; ushort2 u; } c;
  c.h = __float22bfloat162_rn(make_float2(a, b));
  return c.u;
}
static __device__ __forceinline__ float bf2f(unsigned short u) {
  union { unsigned int i; float f; } c;
  c.i = ((unsigned int)u) << 16;
  return c.f;
}

// ---------------- fused prep (352 blocks x 256 thr) ----------------
// blocks 0..255  : hpb rows (2/blk)  hpb[r][k] = bf16(sum_h h[r][h]*W1[h][k] + b1[k])
// blocks 256..287: epf (8 e-rows/blk): ep in frag-record order per e-quarter:
//   epf[q*32768 + (rec*64+s)*8 + j] = ep[e][k], where e = q*64 + (rec>>5)*32
//   + (s&31), k = ((rec&31)*2 + (s>>5))*8 + j   (rec = rt*32+ks)
// blocks 288..351: w2f pack, 32x32x16 B-frag records:
//   record(jg,ks) at w2f[((jg*32+ks)*64+l)*8]: lane l holds
//   W2[k = ks*16 + (l>>5)*8 + u][col = jg*32 + (l&31)], u=0..7
__global__ __launch_bounds__(256) void k_prep(
    const float* __restrict__ h_all, const float* __restrict__ e_feat,
    const float* __restrict__ W1, const float* __restrict__ b1,
    const float* __restrict__ W2,
    unsigned short* __restrict__ hpb, unsigned short* __restrict__ epf,
    unsigned short* __restrict__ w2f) {
  __shared__ float sm[64 * 68];   // 17408 B, reused per role
  const int t = threadIdx.x;
  const int b = blockIdx.x;

  if (b < 256) {                      // ---- hp part: 2 rows, bf16 out
    const int r0 = b * 2;
    float (*hs)[256] = (float(*)[256])sm;
    hs[0][t] = h_all[(size_t)r0 * 256 + t];
    hs[1][t] = h_all[(size_t)(r0 + 1) * 256 + t];
    __syncthreads();
    float2 a0 = make_float2(0.f, 0.f), a1 = make_float2(0.f, 0.f);
    #pragma unroll 2
    for (int k = 0; k < 256; k += 4) {
      float2 w0 = *(const float2*)(W1 + (size_t)k * 512 + 2 * t);
      float2 w1 = *(const float2*)(W1 + (size_t)(k + 1) * 512 + 2 * t);
      float2 w2v = *(const float2*)(W1 + (size_t)(k + 2) * 512 + 2 * t);
      float2 w3v = *(const float2*)(W1 + (size_t)(k + 3) * 512 + 2 * t);
      float h00 = hs[0][k], h01 = hs[0][k + 1], h02 = hs[0][k + 2], h03 = hs[0][k + 3];
      float h10 = hs[1][k], h11 = hs[1][k + 1], h12 = hs[1][k + 2], h13 = hs[1][k + 3];
      a0.x = fmaf(h00, w0.x, a0.x); a0.y = fmaf(h00, w0.y, a0.y);
      a1.x = fmaf(h10, w0.x, a1.x); a1.y = fmaf(h10, w0.y, a1.y);
      a0.x = fmaf(h01, w1.x, a0.x); a0.y = fmaf(h01, w1.y, a0.y);
      a1.x = fmaf(h11, w1.x, a1.x); a1.y = fmaf(h11, w1.y, a1.y);
      a0.x = fmaf(h02, w2v.x, a0.x); a0.y = fmaf(h02, w2v.y, a0.y);
      a1.x = fmaf(h12, w2v.x, a1.x); a1.y = fmaf(h12, w2v.y, a1.y);
      a0.x = fmaf(h03, w3v.x, a0.x); a0.y = fmaf(h03, w3v.y, a0.y);
      a1.x = fmaf(h13, w3v.x, a1.x); a1.y = fmaf(h13, w3v.y, a1.y);
    }
    float2 bv = *(const float2*)(b1 + 2 * t);
    *(ushort2*)(hpb + (size_t)r0 * 512 + 2 * t) = pk_bf16(a0.x + bv.x, a0.y + bv.y);
    *(ushort2*)(hpb + (size_t)(r0 + 1) * 512 + 2 * t) = pk_bf16(a1.x + bv.x, a1.y + bv.y);
  } else if (b < 288) {               // ---- ep part: 8 rows -> epf scatter
    const int r0 = (b - 256) * 8;
    sm[t] = e_feat[(size_t)r0 * 64 + t];
    sm[256 + t] = e_feat[(size_t)r0 * 64 + 256 + t];
    __syncthreads();
    float2 acc[8];
    #pragma unroll
    for (int i = 0; i < 8; ++i) acc[i] = make_float2(0.f, 0.f);
    for (int k = 0; k < 64; ++k) {
      float2 wv = *(const float2*)(W1 + (size_t)(256 + k) * 512 + 2 * t);
      #pragma unroll
      for (int i = 0; i < 8; ++i) {
        acc[i].x = fmaf(sm[i * 64 + k], wv.x, acc[i].x);
        acc[i].y = fmaf(sm[i * 64 + k], wv.y, acc[i].y);
      }
    }
    // scatter into frag-record layout (k = 2t, 2t+1 share one 16B chunk)
    const int k = 2 * t;
    const int ks = k >> 4;            // 0..31
    const int kh = (k >> 3) & 1;
    const int j = k & 7;
    #pragma unroll
    for (int i = 0; i < 8; ++i) {
      const int e = r0 + i;
      const int q = e >> 6, er = e & 63;
      const int rec = (er >> 5) * 32 + ks;
      const int s = (er & 31) + (kh << 5);
      *(ushort2*)(epf + (size_t)q * 32768 + ((size_t)(rec * 64 + s)) * 8 + j) =
          pk_bf16(acc[i].x, acc[i].y);
    }
  } else {                            // ---- w2f pack (32-col records)
    const int bb2 = b - 288;          // 0..63
    const int k0 = (bb2 >> 3) * 64;
    const int c0 = (bb2 & 7) * 64;
    #pragma unroll
    for (int rr = 0; rr < 4; ++rr) {
      const int row = rr * 16 + (t >> 4);
      float4 v = *(const float4*)(W2 + (size_t)(k0 + row) * 512 + c0 + (t & 15) * 4);
      *(float4*)(&sm[row * 68 + (t & 15) * 4]) = v;
    }
    __syncthreads();
    #pragma unroll
    for (int s2 = 0; s2 < 2; ++s2) {
      const int s = t * 2 + s2;       // 0..511 (8 records x 64 lanes)
      const int rec = s >> 6, l = s & 63;
      const int jg = (c0 >> 5) + (rec & 1);
      const int ks = (k0 >> 4) + (rec >> 1);
      const int cl = (rec & 1) * 32 + (l & 31);
      const int kl = (rec >> 1) * 16 + (l >> 5) * 8;
      union { ushort2 o[4]; uint4 v; } u;
      #pragma unroll
      for (int uu = 0; uu < 4; ++uu)
        u.o[uu] = pk_bf16(sm[(kl + 2 * uu) * 68 + cl], sm[(kl + 2 * uu + 1) * 68 + cl]);
      *(uint4*)(w2f + ((size_t)(jg * 32 + ks) * 64 + l) * 8) = u.v;
    }
  }
}

// ---------------- main fused kernel ----------------
// 2048 blocks x 512 thr (8 waves). Block = 64 rows (one bn, e-quarter) x 512
// cols. Wave w: cols w*64 (2 col-tiles of 32). x1 in LDS in 32x32x16
// frag-record order; staging is a LINEAR copy from epf (+ hp broadcast).
__global__ __launch_bounds__(512, 4) void k_main(
    const unsigned short* __restrict__ hpb, const unsigned short* __restrict__ epf,
    const unsigned short* __restrict__ w2f, const float* __restrict__ b2,
    const float* __restrict__ W3, const float* __restrict__ b3,
    float* __restrict__ out) {
  __shared__ unsigned short x1s[64 * 512];   // 64 KiB, frag-record order
  __shared__ float osum[8][64];              // 2 KiB

  const int t = threadIdx.x;
  const int lane = t & 63;
  const int w = t >> 6;            // 0..7 -> col group (64 cols)
  const int l31 = lane & 31;
  const int half = lane >> 5;
  const int bn = blockIdx.x >> 2;
  const int q = blockIdx.x & 3;    // e-quarter

  // ---- B prefetch ring, depth 4 (in flight across staging)
  const unsigned short* wrec0 = w2f + ((size_t)(w * 2 + 0) * 32 * 64 + lane) * 8;
  const unsigned short* wrec1 = w2f + ((size_t)(w * 2 + 1) * 32 * 64 + lane) * 8;
  bf16x8 bb[4][2];
  #pragma unroll
  for (int d = 0; d < 4; ++d) {
    bb[d][0] = *(const bf16x8*)(wrec0 + (size_t)d * 512);
    bb[d][1] = *(const bf16x8*)(wrec1 + (size_t)d * 512);
  }

  // ---- stage x1: linear copy epf -> LDS with relu(hp+ep) convert
  // pass p: flat 16B index f = p*512 + t; read epf[q][f], write x1s[f].
  // hp chunk for (p,t): c = ((p*8+w)&31)*2 + ((t>>5)&1)
  {
    const unsigned short* eq = epf + (size_t)q * 32768;
    const unsigned short* hrow = hpb + (size_t)bn * 512;
    uint4 ev[8], hv[8];
    #pragma unroll
    for (int p = 0; p < 8; ++p) {
      ev[p] = *(const uint4*)(eq + ((size_t)p * 512 + t) * 8);
      const int c = (((p * 8 + w) & 31) << 1) + ((t >> 5) & 1);
      hv[p] = *(const uint4*)(hrow + c * 8);
    }
    #pragma unroll
    for (int p = 0; p < 8; ++p) {
      union { uint4 v; unsigned short s[8]; } e8, h8, ov;
      e8.v = ev[p];
      h8.v = hv[p];
      #pragma unroll
      for (int u = 0; u < 4; ++u) {
        ushort2 pk = pk_bf16(fmaxf(bf2f(e8.s[2 * u]) + bf2f(h8.s[2 * u]), 0.f),
                             fmaxf(bf2f(e8.s[2 * u + 1]) + bf2f(h8.s[2 * u + 1]), 0.f));
        ov.s[2 * u] = pk.x;
        ov.s[2 * u + 1] = pk.y;
      }
      *(uint4*)(&x1s[((size_t)p * 512 + t) * 8]) = ov.v;
    }
  }
  __syncthreads();

  // ---- barrier-free K-loop: 32 steps of K=16, 4 MFMAs (2 rt x 2 ct)
  f32x16 acc[2][2] = {};
  const unsigned short* abase = x1s + (size_t)lane * 8;
  #pragma unroll 8
  for (int ks = 0; ks < 32; ++ks) {
    const int d = ks & 3;
    const int kn = (ks + 4) & 31;    // wraps at end: dummy reload, no OOB
    bf16x8 a0 = *(const bf16x8*)(abase + (size_t)(0 * 32 + ks) * 512);
    bf16x8 a1 = *(const bf16x8*)(abase + (size_t)(1 * 32 + ks) * 512);
    acc[0][0] = __builtin_amdgcn_mfma_f32_32x32x16_bf16(a0, bb[d][0], acc[0][0], 0, 0, 0);
    acc[0][1] = __builtin_amdgcn_mfma_f32_32x32x16_bf16(a0, bb[d][1], acc[0][1], 0, 0, 0);
    acc[1][0] = __builtin_amdgcn_mfma_f32_32x32x16_bf16(a1, bb[d][0], acc[1][0], 0, 0, 0);
    acc[1][1] = __builtin_amdgcn_mfma_f32_32x32x16_bf16(a1, bb[d][1], acc[1][1], 0, 0, 0);
    bb[d][0] = *(const bf16x8*)(wrec0 + (size_t)kn * 512);
    bb[d][1] = *(const bf16x8*)(wrec1 + (size_t)kn * 512);
  }

  // ---- fused epilogue: osum[row] = sum_n relu(acc + b2[n]) * W3[n]
  // C/D 32x32: col = lane&31, row = (reg&3) + 8*(reg>>2) + 4*(lane>>5)
  float b2v[2], w3v[2];
  #pragma unroll
  for (int ct = 0; ct < 2; ++ct) {
    const int n = w * 64 + ct * 32 + l31;
    b2v[ct] = b2[n];
    w3v[ct] = W3[n];
  }
  #pragma unroll
  for (int rt = 0; rt < 2; ++rt) {
    float part[16];
    #pragma unroll
    for (int g = 0; g < 16; ++g) {
      part[g] = fmaf(fmaxf(acc[rt][0][g] + b2v[0], 0.f), w3v[0], 0.f);
      part[g] = fmaf(fmaxf(acc[rt][1][g] + b2v[1], 0.f), w3v[1], part[g]);
    }
    #pragma unroll
    for (int g = 0; g < 16; ++g) {   // reduce over the 32 col-lanes
      float v = part[g];
      v += __shfl_xor(v, 1);
      v += __shfl_xor(v, 2);
      v += __shfl_xor(v, 4);
      v += __shfl_xor(v, 8);
      v += __shfl_xor(v, 16);
      part[g] = v;
    }
    if (l31 == 0) {
      #pragma unroll
      for (int g = 0; g < 16; ++g) {
        const int row = rt * 32 + (g & 3) + 8 * (g >> 2) + 4 * half;
        osum[w][row] = part[g];
      }
    }
  }
  __syncthreads();
  if (t < 64) {
    float s = b3[0];
    #pragma unroll
    for (int ww = 0; ww < 8; ++ww) s += osum[ww][t];
    out[(size_t)bn * 256 + (q << 6) + t] = s;
  }
}

extern "C" void kernel_launch(void* const* d_in, const int* in_sizes, int n_in,
                              void* d_out, int out_size, void* d_ws, size_t ws_size,
                              hipStream_t stream) {
  const float* h_all  = (const float*)d_in[0];   // (8,64,256)
  const float* e_feat = (const float*)d_in[1];   // (256,64)
  const float* W1     = (const float*)d_in[2];   // (320,512)
  const float* b1     = (const float*)d_in[3];   // (512,)
  const float* W2     = (const float*)d_in[4];   // (512,512)
  const float* b2     = (const float*)d_in[5];   // (512,)
  const float* W3     = (const float*)d_in[6];   // (512,1)
  const float* b3     = (const float*)d_in[7];   // (1,)
  float* out = (float*)d_out;                    // 131072 f32

  // ws: hpb 512KB bf16 | epf 256KB bf16 (frag-record) | w2f 512KB bf16
  unsigned short* hpb = (unsigned short*)d_ws;
  unsigned short* epf = hpb + 512 * 512;
  unsigned short* w2f = epf + 256 * 512;

  hipLaunchKernelGGL(k_prep, dim3(352), dim3(256), 0, stream,
                     h_all, e_feat, W1, b1, W2, hpb, epf, w2f);
  hipLaunchKernelGGL(k_main, dim3(2048), dim3(512), 0, stream,
                     hpb, epf, w2f, b2, W3, b3, out);
}